// Round 1
// baseline (755.400 us; speedup 1.0000x reference)
//
#include <hip/hip_runtime.h>

#define CH 128
#define BN_EPS 1e-5f

// ---------------------------------------------------------------------------
// Detect whether edge_index was delivered as int64 (raw) or int32 (converted).
// int64 little-endian values < 2^31 have all-zero high words -> odd int32
// words all zero. int32 indices are random in [0,50000) -> some odd word != 0.
__global__ void sage_detect(const int* __restrict__ ei, int* __restrict__ flag) {
    int v = ei[threadIdx.x * 2 + 1];
    unsigned long long ballot = __ballot(v != 0);
    if (threadIdx.x == 0) flag[0] = (ballot == 0ULL) ? 1 : 0;  // 1 => int64
}

// ---------------------------------------------------------------------------
// agg[dst][c] += x[src][c]; deg[dst] += 1.  One thread per (edge, channel).
__global__ __launch_bounds__(256) void sage_scatter(
    const float* __restrict__ x,
    const void* __restrict__ ei,
    const int* __restrict__ flag,
    float* __restrict__ agg,
    float* __restrict__ deg,
    int nEdges)
{
    int idx = blockIdx.x * 256 + threadIdx.x;   // < 102.4M, fits int32
    int e = idx >> 7;
    if (e >= nEdges) return;
    int c = idx & 127;
    int s, d;
    if (flag[0]) {
        const long long* p = (const long long*)ei;
        s = (int)p[e];
        d = (int)p[nEdges + e];
    } else {
        const int* p = (const int*)ei;
        s = p[e];
        d = p[nEdges + e];
    }
    atomicAdd(&agg[(size_t)d * CH + c], x[(size_t)s * CH + c]);
    if (c == 0) atomicAdd(&deg[d], 1.0f);
}

// ---------------------------------------------------------------------------
// h[n][co] = (1/max(deg,1)) * dot(agg[n], Wl[co]) + bl[co] + dot(x[n], Wr[co])
// Both W^T staged in LDS (128 KiB). Block = 256 threads = 2 nodes x 128 ch.
// Fused BN partial sums (sum, sumsq per channel) -> 1 atomic/channel/block.
__global__ __launch_bounds__(256) void sage_linear(
    const float* __restrict__ x,
    const float* __restrict__ agg,
    const float* __restrict__ deg,
    const float* __restrict__ Wl,
    const float* __restrict__ bl,
    const float* __restrict__ Wr,
    float* __restrict__ h,
    float* __restrict__ bn_sum,
    float* __restrict__ bn_sumsq,
    int nNodes)
{
    __shared__ float WlT[CH * CH];   // 64 KiB: WlT[k*CH+co] = Wl[co][k]
    __shared__ float WrT[CH * CH];   // 64 KiB
    __shared__ float av[2][CH];
    __shared__ float xv[2][CH];
    __shared__ float red[2][CH];

    int tid = threadIdx.x;
    for (int i = tid; i < CH * CH; i += 256) {
        int r = i >> 7;          // output channel (row of W)
        int c = i & 127;         // k
        WlT[c * CH + r] = Wl[i];
        WrT[c * CH + r] = Wr[i];
    }
    __syncthreads();

    int sub = tid >> 7;          // which of the 2 nodes
    int co  = tid & 127;         // output channel
    float bias = bl[co];
    float s_acc = 0.f, ss_acc = 0.f;

    for (int base = blockIdx.x * 2; base < nNodes; base += gridDim.x * 2) {
        int n = base + sub;
        bool valid = (n < nNodes);
        if (valid) {
            av[sub][co] = agg[(size_t)n * CH + co];
            xv[sub][co] = x[(size_t)n * CH + co];
        }
        __syncthreads();
        if (valid) {
            float inv = 1.0f / fmaxf(deg[n], 1.0f);
            float a1 = 0.f, a2 = 0.f;
            #pragma unroll
            for (int k = 0; k < CH; k += 4) {
                float4 a4 = *reinterpret_cast<const float4*>(&av[sub][k]);
                float4 x4 = *reinterpret_cast<const float4*>(&xv[sub][k]);
                a1 += a4.x * WlT[(k + 0) * CH + co];
                a1 += a4.y * WlT[(k + 1) * CH + co];
                a1 += a4.z * WlT[(k + 2) * CH + co];
                a1 += a4.w * WlT[(k + 3) * CH + co];
                a2 += x4.x * WrT[(k + 0) * CH + co];
                a2 += x4.y * WrT[(k + 1) * CH + co];
                a2 += x4.z * WrT[(k + 2) * CH + co];
                a2 += x4.w * WrT[(k + 3) * CH + co];
            }
            float hv = a1 * inv + bias + a2;
            h[(size_t)n * CH + co] = hv;
            s_acc += hv;
            ss_acc += hv * hv;
        }
        __syncthreads();
    }

    // combine the two sub-halves, one atomic per channel per block
    red[sub][co] = s_acc;
    __syncthreads();
    if (sub == 0) atomicAdd(&bn_sum[co], red[0][co] + red[1][co]);
    __syncthreads();
    red[sub][co] = ss_acc;
    __syncthreads();
    if (sub == 0) atomicAdd(&bn_sumsq[co], red[0][co] + red[1][co]);
}

// ---------------------------------------------------------------------------
__global__ void sage_finalize(
    const float* __restrict__ bn_sum,
    const float* __restrict__ bn_sumsq,
    const float* __restrict__ gamma,
    const float* __restrict__ beta,
    float* __restrict__ scaleshift,
    int nNodes)
{
    int c = threadIdx.x;
    float invN = 1.0f / (float)nNodes;
    float mu = bn_sum[c] * invN;
    float var = bn_sumsq[c] * invN - mu * mu;
    var = fmaxf(var, 0.f);
    float sc = gamma[c] * rsqrtf(var + BN_EPS);
    scaleshift[c] = sc;
    scaleshift[CH + c] = beta[c] - mu * sc;
}

// ---------------------------------------------------------------------------
__global__ __launch_bounds__(256) void sage_apply(
    float* __restrict__ h,
    const float* __restrict__ scaleshift,
    int total4)
{
    int i = blockIdx.x * 256 + threadIdx.x;
    if (i >= total4) return;
    float4 v = reinterpret_cast<float4*>(h)[i];
    int c = (i * 4) & 127;
    float4 sc = *reinterpret_cast<const float4*>(&scaleshift[c]);
    float4 sh = *reinterpret_cast<const float4*>(&scaleshift[CH + c]);
    v.x = fmaxf(fmaf(v.x, sc.x, sh.x), 0.f);
    v.y = fmaxf(fmaf(v.y, sc.y, sh.y), 0.f);
    v.z = fmaxf(fmaf(v.z, sc.z, sh.z), 0.f);
    v.w = fmaxf(fmaf(v.w, sc.w, sh.w), 0.f);
    reinterpret_cast<float4*>(h)[i] = v;
}

// ---------------------------------------------------------------------------
extern "C" void kernel_launch(void* const* d_in, const int* in_sizes, int n_in,
                              void* d_out, int out_size, void* d_ws, size_t ws_size,
                              hipStream_t stream)
{
    const float* x     = (const float*)d_in[0];
    const void*  ei    = d_in[1];
    const float* Wl    = (const float*)d_in[2];
    const float* bl    = (const float*)d_in[3];
    const float* Wr    = (const float*)d_in[4];
    const float* gamma = (const float*)d_in[5];
    const float* beta  = (const float*)d_in[6];

    int nNodes = in_sizes[0] / CH;
    int nEdges = in_sizes[1] / 2;

    float* ws         = (float*)d_ws;
    float* agg        = ws;                                  // N*CH
    float* deg        = agg + (size_t)nNodes * CH;           // N
    float* bn_sum     = deg + nNodes;                        // CH
    float* bn_sumsq   = bn_sum + CH;                         // CH
    float* scaleshift = bn_sumsq + CH;                       // 2*CH
    int*   flag       = (int*)(scaleshift + 2 * CH);         // 1

    float* h = (float*)d_out;                                // reuse d_out for h

    size_t zeroBytes = ((size_t)nNodes * CH + nNodes + 2 * CH) * sizeof(float);
    hipMemsetAsync(d_ws, 0, zeroBytes, stream);

    sage_detect<<<1, 64, 0, stream>>>((const int*)ei, flag);

    int totalScatter = nEdges * CH;  // 102,400,000
    sage_scatter<<<(totalScatter + 255) / 256, 256, 0, stream>>>(
        x, ei, flag, agg, deg, nEdges);

    sage_linear<<<1024, 256, 0, stream>>>(
        x, agg, deg, Wl, bl, Wr, h, bn_sum, bn_sumsq, nNodes);

    sage_finalize<<<1, CH, 0, stream>>>(
        bn_sum, bn_sumsq, gamma, beta, scaleshift, nNodes);

    int total4 = nNodes * CH / 4;
    sage_apply<<<(total4 + 255) / 256, 256, 0, stream>>>(h, scaleshift, total4);
}

// Round 2
// 441.931 us; speedup vs baseline: 1.7093x; 1.7093x over previous
//
#include <hip/hip_runtime.h>

#define CH 128
#define BN_EPS 1e-5f

typedef unsigned int uint32;
typedef unsigned short ushort16;
using f32x4  = __attribute__((ext_vector_type(4))) float;
using bf16x8 = __attribute__((ext_vector_type(8))) short;

__device__ __forceinline__ ushort16 f2b(float f) {
    uint32 u = __float_as_uint(f);
    return (ushort16)((u + 0x7FFFu + ((u >> 16) & 1u)) >> 16);   // RNE
}
__device__ __forceinline__ float blo(uint32 u) { return __uint_as_float(u << 16); }
__device__ __forceinline__ float bhi(uint32 u) { return __uint_as_float(u & 0xFFFF0000u); }

// ---------------------------------------------------------------------------
// int64 vs int32 edge_index detection (see round-0 note).
__global__ void sage_detect(const int* __restrict__ ei, int* __restrict__ flag) {
    int v = ei[threadIdx.x * 2 + 1];
    unsigned long long ballot = __ballot(v != 0);
    if (threadIdx.x == 0) flag[0] = (ballot == 0ULL) ? 1 : 0;  // 1 => int64
}

__device__ __forceinline__ void load_edge(const void* ei, const int* flag, int e,
                                          int nEdges, int& s, int& d) {
    if (flag[0]) {
        const long long* p = (const long long*)ei;
        s = (int)p[e];
        d = (int)p[nEdges + e];
    } else {
        const int* p = (const int*)ei;
        s = p[e];
        d = p[nEdges + e];
    }
}

// ---------------------------------------------------------------------------
__global__ __launch_bounds__(256) void sage_hist(
    const void* __restrict__ ei, const int* __restrict__ flag,
    int* __restrict__ hist, int nEdges)
{
    int e = blockIdx.x * 256 + threadIdx.x;
    if (e >= nEdges) return;
    int s, d;
    load_edge(ei, flag, e, nEdges, s, d);
    atomicAdd(&hist[d], 1);
}

// ---------------------------------------------------------------------------
// Single-block exclusive/inclusive scan -> rowptr[N+1], cursor[N].
__global__ __launch_bounds__(1024) void sage_scan(
    const int* __restrict__ hist, int* __restrict__ rowptr,
    int* __restrict__ cursor, int nNodes)
{
    __shared__ int wsum[16];
    __shared__ int carrySh;
    int tid = threadIdx.x, lane = tid & 63, wid = tid >> 6;
    if (tid == 0) { carrySh = 0; rowptr[0] = 0; }
    __syncthreads();
    for (int base = 0; base < nNodes; base += 1024) {
        int i = base + tid;
        int v = (i < nNodes) ? hist[i] : 0;
        int inc = v;
        #pragma unroll
        for (int off = 1; off < 64; off <<= 1) {
            int t = __shfl_up(inc, off);
            if (lane >= off) inc += t;
        }
        if (lane == 63) wsum[wid] = inc;
        __syncthreads();
        if (wid == 0) {
            int wv = (lane < 16) ? wsum[lane] : 0;
            #pragma unroll
            for (int off = 1; off < 16; off <<= 1) {
                int t = __shfl_up(wv, off);
                if (lane >= off) wv += t;
            }
            if (lane < 16) wsum[lane] = wv;
        }
        __syncthreads();
        int waveOff = (wid > 0) ? wsum[wid - 1] : 0;
        int carry = carrySh;
        int inclusive = carry + waveOff + inc;
        if (i < nNodes) { rowptr[i + 1] = inclusive; cursor[i] = inclusive - v; }
        __syncthreads();
        if (tid == 1023) carrySh = carry + wsum[15];
        __syncthreads();
    }
}

// ---------------------------------------------------------------------------
__global__ __launch_bounds__(256) void sage_fill(
    const void* __restrict__ ei, const int* __restrict__ flag,
    int* __restrict__ cursor, int* __restrict__ colidx, int nEdges)
{
    int e = blockIdx.x * 256 + threadIdx.x;
    if (e >= nEdges) return;
    int s, d;
    load_edge(ei, flag, e, nEdges, s, d);
    int pos = atomicAdd(&cursor[d], 1);
    colidx[pos] = s;
}

// ---------------------------------------------------------------------------
// x (f32) -> xb (bf16), 8 elems/thread.
__global__ __launch_bounds__(256) void sage_convert(
    const float* __restrict__ x, uint32* __restrict__ xb4, int total8)
{
    int i = blockIdx.x * 256 + threadIdx.x;
    if (i >= total8) return;
    const float4* x4 = (const float4*)x;
    float4 a = x4[2 * i], b = x4[2 * i + 1];
    uint4 o;
    o.x = (uint32)f2b(a.x) | ((uint32)f2b(a.y) << 16);
    o.y = (uint32)f2b(a.z) | ((uint32)f2b(a.w) << 16);
    o.z = (uint32)f2b(b.x) | ((uint32)f2b(b.y) << 16);
    o.w = (uint32)f2b(b.z) | ((uint32)f2b(b.w) << 16);
    ((uint4*)xb4)[i] = o;
}

// ---------------------------------------------------------------------------
// WcT[co][k] bf16, k<128 -> W_r[co][k], k>=128 -> W_l[co][k-128].
__global__ __launch_bounds__(256) void sage_prep_wct(
    const float* __restrict__ Wl, const float* __restrict__ Wr,
    ushort16* __restrict__ wct)
{
    int idx = blockIdx.x * 256 + threadIdx.x;   // < 128*256
    int co = idx >> 8, k = idx & 255;
    float v = (k < 128) ? Wr[co * 128 + k] : Wl[co * 128 + (k - 128)];
    wct[idx] = f2b(v);
}

// ---------------------------------------------------------------------------
// CSR gather: one wave per node. mean_b[n] = bf16(mean of xb[neighbors]).
__global__ __launch_bounds__(256) void sage_aggregate(
    const ushort16* __restrict__ xb, const int* __restrict__ rowptr,
    const int* __restrict__ colidx, uint32* __restrict__ mean_b, int nNodes)
{
    int node = blockIdx.x * 4 + (threadIdx.x >> 6);
    if (node >= nNodes) return;
    int lane = threadIdx.x & 63;
    int start = rowptr[node], end = rowptr[node + 1];
    float ax = 0.f, ay = 0.f;
    for (int base = start; base < end; base += 64) {
        int idx = base + lane;
        int src = (idx < end) ? colidx[idx] : 0;
        int cnt = min(end - base, 64);
        for (int e = 0; e < cnt; ++e) {
            int sn = __shfl(src, e);
            uint32 u = *(const uint32*)((const ushort16*)xb + (size_t)sn * CH + lane * 2);
            ax += blo(u);
            ay += bhi(u);
        }
    }
    float inv = 1.0f / fmaxf((float)(end - start), 1.0f);
    uint32 o = (uint32)f2b(ax * inv) | ((uint32)f2b(ay * inv) << 16);
    mean_b[(size_t)node * (CH / 2) + lane] = o;
}

// ---------------------------------------------------------------------------
// h[n][co] = sum_k Xc[n][k] * WcT[co][k] + bl[co], Xc = [xb | mean_b] (K=256).
// MFMA 16x16x32 bf16. Block = 256 thr = 4 waves x 16 rows = 64 rows, all 128 co.
// Fused BN partials (sum, sumsq per channel) -> partials[block][256].
__global__ __launch_bounds__(256) void sage_gemm(
    const ushort16* __restrict__ xb, const ushort16* __restrict__ mean_b,
    const ushort16* __restrict__ wct, const float* __restrict__ bl,
    float* __restrict__ h, float* __restrict__ partials, int nNodes)
{
    __shared__ float redS[4][CH];
    __shared__ float redQ[4][CH];

    int tid = threadIdx.x;
    int wave = tid >> 6, lane = tid & 63;
    int col = lane & 15, kg = lane >> 4;
    int rowBase = blockIdx.x * 64 + wave * 16;

    int arow = min(rowBase + col, nNodes - 1);          // A-frag row = lane&15
    const ushort16* xrow = xb + (size_t)arow * CH;
    const ushort16* mrow = mean_b + (size_t)arow * CH;

    f32x4 acc[8];
    #pragma unroll
    for (int cb = 0; cb < 8; ++cb) acc[cb] = (f32x4){0.f, 0.f, 0.f, 0.f};

    #pragma unroll
    for (int kstep = 0; kstep < 8; ++kstep) {
        const ushort16* asrc = (kstep < 4) ? (xrow + kstep * 32 + kg * 8)
                                           : (mrow + (kstep - 4) * 32 + kg * 8);
        bf16x8 a = *(const bf16x8*)asrc;
        #pragma unroll
        for (int cb = 0; cb < 8; ++cb) {
            const ushort16* bsrc = wct + (size_t)(cb * 16 + col) * 256 + kstep * 32 + kg * 8;
            bf16x8 b = *(const bf16x8*)bsrc;
            acc[cb] = __builtin_amdgcn_mfma_f32_16x16x32_bf16(a, b, acc[cb], 0, 0, 0);
        }
    }

    // epilogue: bias, store h, BN partial sums
    #pragma unroll
    for (int cb = 0; cb < 8; ++cb) {
        int co = cb * 16 + col;
        float blv = bl[co];
        float s = 0.f, ss = 0.f;
        #pragma unroll
        for (int j = 0; j < 4; ++j) {
            int r = rowBase + kg * 4 + j;               // C row = (lane>>4)*4+j
            float v = acc[cb][j] + blv;
            if (r < nNodes) {
                h[(size_t)r * CH + co] = v;
                s += v;
                ss += v * v;
            }
        }
        s  += __shfl_xor(s, 16);  s  += __shfl_xor(s, 32);
        ss += __shfl_xor(ss, 16); ss += __shfl_xor(ss, 32);
        if (kg == 0) { redS[wave][co] = s; redQ[wave][co] = ss; }
    }
    __syncthreads();
    if (tid < CH) {
        float t = redS[0][tid] + redS[1][tid] + redS[2][tid] + redS[3][tid];
        partials[(size_t)blockIdx.x * 256 + tid] = t;
    } else {
        int c = tid - CH;
        float t = redQ[0][c] + redQ[1][c] + redQ[2][c] + redQ[3][c];
        partials[(size_t)blockIdx.x * 256 + CH + c] = t;
    }
}

// ---------------------------------------------------------------------------
__global__ __launch_bounds__(256) void sage_bn_finalize(
    const float* __restrict__ partials, const float* __restrict__ gamma,
    const float* __restrict__ beta, float* __restrict__ scaleshift,
    int nBlk, int nNodes)
{
    __shared__ float sums[256];
    int tid = threadIdx.x;
    int c = tid & 127, half = tid >> 7;
    float acc = 0.f;
    for (int b = 0; b < nBlk; ++b) acc += partials[(size_t)b * 256 + half * CH + c];
    sums[half * CH + c] = acc;
    __syncthreads();
    if (tid < CH) {
        float invN = 1.0f / (float)nNodes;
        float mu = sums[tid] * invN;
        float var = sums[CH + tid] * invN - mu * mu;
        var = fmaxf(var, 0.f);
        float sc = gamma[tid] * rsqrtf(var + BN_EPS);
        scaleshift[tid] = sc;
        scaleshift[CH + tid] = beta[tid] - mu * sc;
    }
}

// ---------------------------------------------------------------------------
__global__ __launch_bounds__(256) void sage_apply(
    float* __restrict__ h, const float* __restrict__ scaleshift, int total4)
{
    int i = blockIdx.x * 256 + threadIdx.x;
    if (i >= total4) return;
    float4 v = reinterpret_cast<float4*>(h)[i];
    int c = (i * 4) & 127;
    float4 sc = *reinterpret_cast<const float4*>(&scaleshift[c]);
    float4 sh = *reinterpret_cast<const float4*>(&scaleshift[CH + c]);
    v.x = fmaxf(fmaf(v.x, sc.x, sh.x), 0.f);
    v.y = fmaxf(fmaf(v.y, sc.y, sh.y), 0.f);
    v.z = fmaxf(fmaf(v.z, sc.z, sh.z), 0.f);
    v.w = fmaxf(fmaf(v.w, sc.w, sh.w), 0.f);
    reinterpret_cast<float4*>(h)[i] = v;
}

// ---------------------------------------------------------------------------
extern "C" void kernel_launch(void* const* d_in, const int* in_sizes, int n_in,
                              void* d_out, int out_size, void* d_ws, size_t ws_size,
                              hipStream_t stream)
{
    const float* x     = (const float*)d_in[0];
    const void*  ei    = d_in[1];
    const float* Wl    = (const float*)d_in[2];
    const float* bl    = (const float*)d_in[3];
    const float* Wr    = (const float*)d_in[4];
    const float* gamma = (const float*)d_in[5];
    const float* beta  = (const float*)d_in[6];

    int nNodes = in_sizes[0] / CH;
    int nEdges = in_sizes[1] / 2;
    int nBlkM  = (nNodes + 63) / 64;

    // ws layout (256B-aligned slabs)
    char* p = (char*)d_ws;
    auto take = [&](size_t bytes) {
        char* r = p;
        p += (bytes + 255) & ~(size_t)255;
        return r;
    };
    ushort16* xb      = (ushort16*)take((size_t)nNodes * CH * 2);      // 12.8 MB
    ushort16* mean_b  = (ushort16*)take((size_t)nNodes * CH * 2);      // 12.8 MB
    ushort16* wct     = (ushort16*)take((size_t)CH * 256 * 2);         // 64 KB
    int*      hist    = (int*)take((size_t)nNodes * 4);
    int*      rowptr  = (int*)take((size_t)(nNodes + 1) * 4);
    int*      cursor  = (int*)take((size_t)nNodes * 4);
    int*      colidx  = (int*)take((size_t)nEdges * 4);                // 3.2 MB
    float*    partials= (float*)take((size_t)nBlkM * 256 * 4);         // 0.8 MB
    float*    scaless = (float*)take(256 * 4);
    int*      flag    = (int*)take(4);

    float* h = (float*)d_out;

    hipMemsetAsync(hist, 0, (size_t)nNodes * 4, stream);
    sage_detect<<<1, 64, 0, stream>>>((const int*)ei, flag);

    int eBlocks = (nEdges + 255) / 256;
    sage_hist<<<eBlocks, 256, 0, stream>>>(ei, flag, hist, nEdges);
    sage_scan<<<1, 1024, 0, stream>>>(hist, rowptr, cursor, nNodes);
    sage_fill<<<eBlocks, 256, 0, stream>>>(ei, flag, cursor, colidx, nEdges);

    int total8 = nNodes * CH / 8;
    sage_convert<<<(total8 + 255) / 256, 256, 0, stream>>>(x, (uint32*)xb, total8);
    sage_prep_wct<<<(CH * 256) / 256, 256, 0, stream>>>(Wl, Wr, wct);

    sage_aggregate<<<(nNodes + 3) / 4, 256, 0, stream>>>(
        xb, rowptr, colidx, (uint32*)mean_b, nNodes);

    sage_gemm<<<nBlkM, 256, 0, stream>>>(xb, mean_b, wct, bl, h, partials, nNodes);

    sage_bn_finalize<<<1, 256, 0, stream>>>(partials, gamma, beta, scaless, nBlkM, nNodes);

    int total4 = nNodes * CH / 4;
    sage_apply<<<(total4 + 255) / 256, 256, 0, stream>>>(h, scaless, total4);
}

// Round 3
// 272.228 us; speedup vs baseline: 2.7749x; 1.6234x over previous
//
#include <hip/hip_runtime.h>

#define CH 128
#define BN_EPS 1e-5f

typedef unsigned int uint32;
typedef unsigned short ushort16;
using f32x4  = __attribute__((ext_vector_type(4))) float;
using bf16x8 = __attribute__((ext_vector_type(8))) short;

__device__ __forceinline__ ushort16 f2b(float f) {
    uint32 u = __float_as_uint(f);
    return (ushort16)((u + 0x7FFFu + ((u >> 16) & 1u)) >> 16);   // RNE
}
__device__ __forceinline__ float blo(uint32 u) { return __uint_as_float(u << 16); }
__device__ __forceinline__ float bhi(uint32 u) { return __uint_as_float(u & 0xFFFF0000u); }

// ---------------------------------------------------------------------------
// int64 vs int32 edge_index detection (see round-0 note).
__global__ void sage_detect(const int* __restrict__ ei, int* __restrict__ flag) {
    int v = ei[threadIdx.x * 2 + 1];
    unsigned long long ballot = __ballot(v != 0);
    if (threadIdx.x == 0) flag[0] = (ballot == 0ULL) ? 1 : 0;  // 1 => int64
}

__device__ __forceinline__ void load_edge(const void* ei, const int* flag, int e,
                                          int nEdges, int& s, int& d) {
    if (flag[0]) {
        const long long* p = (const long long*)ei;
        s = (int)p[e];
        d = (int)p[nEdges + e];
    } else {
        const int* p = (const int*)ei;
        s = p[e];
        d = p[nEdges + e];
    }
}

// ---------------------------------------------------------------------------
__global__ __launch_bounds__(256) void sage_hist(
    const void* __restrict__ ei, const int* __restrict__ flag,
    int* __restrict__ hist, int nEdges)
{
    int e = blockIdx.x * 256 + threadIdx.x;
    if (e >= nEdges) return;
    int s, d;
    load_edge(ei, flag, e, nEdges, s, d);
    atomicAdd(&hist[d], 1);
}

// ---------------------------------------------------------------------------
// Single-block exclusive/inclusive scan -> rowptr[N+1], cursor[N].
__global__ __launch_bounds__(1024) void sage_scan(
    const int* __restrict__ hist, int* __restrict__ rowptr,
    int* __restrict__ cursor, int nNodes)
{
    __shared__ int wsum[16];
    __shared__ int carrySh;
    int tid = threadIdx.x, lane = tid & 63, wid = tid >> 6;
    if (tid == 0) { carrySh = 0; rowptr[0] = 0; }
    __syncthreads();
    for (int base = 0; base < nNodes; base += 1024) {
        int i = base + tid;
        int v = (i < nNodes) ? hist[i] : 0;
        int inc = v;
        #pragma unroll
        for (int off = 1; off < 64; off <<= 1) {
            int t = __shfl_up(inc, off);
            if (lane >= off) inc += t;
        }
        if (lane == 63) wsum[wid] = inc;
        __syncthreads();
        if (wid == 0) {
            int wv = (lane < 16) ? wsum[lane] : 0;
            #pragma unroll
            for (int off = 1; off < 16; off <<= 1) {
                int t = __shfl_up(wv, off);
                if (lane >= off) wv += t;
            }
            if (lane < 16) wsum[lane] = wv;
        }
        __syncthreads();
        int waveOff = (wid > 0) ? wsum[wid - 1] : 0;
        int carry = carrySh;
        int inclusive = carry + waveOff + inc;
        if (i < nNodes) { rowptr[i + 1] = inclusive; cursor[i] = inclusive - v; }
        __syncthreads();
        if (tid == 1023) carrySh = carry + wsum[15];
        __syncthreads();
    }
}

// ---------------------------------------------------------------------------
__global__ __launch_bounds__(256) void sage_fill(
    const void* __restrict__ ei, const int* __restrict__ flag,
    int* __restrict__ cursor, int* __restrict__ colidx, int nEdges)
{
    int e = blockIdx.x * 256 + threadIdx.x;
    if (e >= nEdges) return;
    int s, d;
    load_edge(ei, flag, e, nEdges, s, d);
    int pos = atomicAdd(&cursor[d], 1);
    colidx[pos] = s;
}

// ---------------------------------------------------------------------------
// x (f32) -> xb (bf16), 8 elems/thread.
__global__ __launch_bounds__(256) void sage_convert(
    const float* __restrict__ x, uint32* __restrict__ xb4, int total8)
{
    int i = blockIdx.x * 256 + threadIdx.x;
    if (i >= total8) return;
    const float4* x4 = (const float4*)x;
    float4 a = x4[2 * i], b = x4[2 * i + 1];
    uint4 o;
    o.x = (uint32)f2b(a.x) | ((uint32)f2b(a.y) << 16);
    o.y = (uint32)f2b(a.z) | ((uint32)f2b(a.w) << 16);
    o.z = (uint32)f2b(b.x) | ((uint32)f2b(b.y) << 16);
    o.w = (uint32)f2b(b.z) | ((uint32)f2b(b.w) << 16);
    ((uint4*)xb4)[i] = o;
}

// ---------------------------------------------------------------------------
// WcT[co][k] bf16, k<128 -> W_r[co][k], k>=128 -> W_l[co][k-128].
__global__ __launch_bounds__(256) void sage_prep_wct(
    const float* __restrict__ Wl, const float* __restrict__ Wr,
    ushort16* __restrict__ wct)
{
    int idx = blockIdx.x * 256 + threadIdx.x;   // < 128*256
    int co = idx >> 8, k = idx & 255;
    float v = (k < 128) ? Wr[co * 128 + k] : Wl[co * 128 + (k - 128)];
    wct[idx] = f2b(v);
}

// ---------------------------------------------------------------------------
// CSR gather: one wave per node. mean_b[n] = bf16(mean of xb[neighbors]).
__global__ __launch_bounds__(256) void sage_aggregate(
    const ushort16* __restrict__ xb, const int* __restrict__ rowptr,
    const int* __restrict__ colidx, uint32* __restrict__ mean_b, int nNodes)
{
    int node = blockIdx.x * 4 + (threadIdx.x >> 6);
    if (node >= nNodes) return;
    int lane = threadIdx.x & 63;
    int start = rowptr[node], end = rowptr[node + 1];
    float ax = 0.f, ay = 0.f;
    for (int base = start; base < end; base += 64) {
        int idx = base + lane;
        int src = (idx < end) ? colidx[idx] : 0;
        int cnt = min(end - base, 64);
        for (int e = 0; e < cnt; ++e) {
            int sn = __shfl(src, e);
            uint32 u = *(const uint32*)((const ushort16*)xb + (size_t)sn * CH + lane * 2);
            ax += blo(u);
            ay += bhi(u);
        }
    }
    float inv = 1.0f / fmaxf((float)(end - start), 1.0f);
    uint32 o = (uint32)f2b(ax * inv) | ((uint32)f2b(ay * inv) << 16);
    mean_b[(size_t)node * (CH / 2) + lane] = o;
}

// ---------------------------------------------------------------------------
// h[n][co] = sum_k Xc[n][k] * WcT[co][k] + bl[co], Xc = [xb | mean_b] (K=256).
// MFMA 16x16x32 bf16. Block = 256 thr = 4 waves x 16 rows = 64 rows, all 128 co.
// Fused BN partials -> one atomicAdd per channel per block (256 addrs, ~2us).
__global__ __launch_bounds__(256) void sage_gemm(
    const ushort16* __restrict__ xb, const ushort16* __restrict__ mean_b,
    const ushort16* __restrict__ wct, const float* __restrict__ bl,
    float* __restrict__ h, float* __restrict__ bn_sum, float* __restrict__ bn_sumsq,
    int nNodes)
{
    __shared__ float redS[4][CH];
    __shared__ float redQ[4][CH];

    int tid = threadIdx.x;
    int wave = tid >> 6, lane = tid & 63;
    int col = lane & 15, kg = lane >> 4;
    int rowBase = blockIdx.x * 64 + wave * 16;

    int arow = min(rowBase + col, nNodes - 1);          // A-frag row = lane&15
    const ushort16* xrow = xb + (size_t)arow * CH;
    const ushort16* mrow = mean_b + (size_t)arow * CH;

    f32x4 acc[8];
    #pragma unroll
    for (int cb = 0; cb < 8; ++cb) acc[cb] = (f32x4){0.f, 0.f, 0.f, 0.f};

    #pragma unroll
    for (int kstep = 0; kstep < 8; ++kstep) {
        const ushort16* asrc = (kstep < 4) ? (xrow + kstep * 32 + kg * 8)
                                           : (mrow + (kstep - 4) * 32 + kg * 8);
        bf16x8 a = *(const bf16x8*)asrc;
        #pragma unroll
        for (int cb = 0; cb < 8; ++cb) {
            const ushort16* bsrc = wct + (size_t)(cb * 16 + col) * 256 + kstep * 32 + kg * 8;
            bf16x8 b = *(const bf16x8*)bsrc;
            acc[cb] = __builtin_amdgcn_mfma_f32_16x16x32_bf16(a, b, acc[cb], 0, 0, 0);
        }
    }

    // epilogue: bias, store h, BN partial sums
    #pragma unroll
    for (int cb = 0; cb < 8; ++cb) {
        int co = cb * 16 + col;
        float blv = bl[co];
        float s = 0.f, ss = 0.f;
        #pragma unroll
        for (int j = 0; j < 4; ++j) {
            int r = rowBase + kg * 4 + j;               // C row = (lane>>4)*4+j
            float v = acc[cb][j] + blv;
            if (r < nNodes) {
                h[(size_t)r * CH + co] = v;
                s += v;
                ss += v * v;
            }
        }
        s  += __shfl_xor(s, 16);  s  += __shfl_xor(s, 32);
        ss += __shfl_xor(ss, 16); ss += __shfl_xor(ss, 32);
        if (kg == 0) { redS[wave][co] = s; redQ[wave][co] = ss; }
    }
    __syncthreads();
    if (tid < CH) {
        atomicAdd(&bn_sum[tid], redS[0][tid] + redS[1][tid] + redS[2][tid] + redS[3][tid]);
    } else {
        int c = tid - CH;
        atomicAdd(&bn_sumsq[c], redQ[0][c] + redQ[1][c] + redQ[2][c] + redQ[3][c]);
    }
}

// ---------------------------------------------------------------------------
__global__ void sage_finalize(
    const float* __restrict__ bn_sum, const float* __restrict__ bn_sumsq,
    const float* __restrict__ gamma, const float* __restrict__ beta,
    float* __restrict__ scaleshift, int nNodes)
{
    int c = threadIdx.x;
    float invN = 1.0f / (float)nNodes;
    float mu = bn_sum[c] * invN;
    float var = bn_sumsq[c] * invN - mu * mu;
    var = fmaxf(var, 0.f);
    float sc = gamma[c] * rsqrtf(var + BN_EPS);
    scaleshift[c] = sc;
    scaleshift[CH + c] = beta[c] - mu * sc;
}

// ---------------------------------------------------------------------------
__global__ __launch_bounds__(256) void sage_apply(
    float* __restrict__ h, const float* __restrict__ scaleshift, int total4)
{
    int i = blockIdx.x * 256 + threadIdx.x;
    if (i >= total4) return;
    float4 v = reinterpret_cast<float4*>(h)[i];
    int c = (i * 4) & 127;
    float4 sc = *reinterpret_cast<const float4*>(&scaleshift[c]);
    float4 sh = *reinterpret_cast<const float4*>(&scaleshift[CH + c]);
    v.x = fmaxf(fmaf(v.x, sc.x, sh.x), 0.f);
    v.y = fmaxf(fmaf(v.y, sc.y, sh.y), 0.f);
    v.z = fmaxf(fmaf(v.z, sc.z, sh.z), 0.f);
    v.w = fmaxf(fmaf(v.w, sc.w, sh.w), 0.f);
    reinterpret_cast<float4*>(h)[i] = v;
}

// ---------------------------------------------------------------------------
extern "C" void kernel_launch(void* const* d_in, const int* in_sizes, int n_in,
                              void* d_out, int out_size, void* d_ws, size_t ws_size,
                              hipStream_t stream)
{
    const float* x     = (const float*)d_in[0];
    const void*  ei    = d_in[1];
    const float* Wl    = (const float*)d_in[2];
    const float* bl    = (const float*)d_in[3];
    const float* Wr    = (const float*)d_in[4];
    const float* gamma = (const float*)d_in[5];
    const float* beta  = (const float*)d_in[6];

    int nNodes = in_sizes[0] / CH;
    int nEdges = in_sizes[1] / 2;
    int nBlkM  = (nNodes + 63) / 64;

    // ws layout (256B-aligned slabs)
    char* p = (char*)d_ws;
    auto take = [&](size_t bytes) {
        char* r = p;
        p += (bytes + 255) & ~(size_t)255;
        return r;
    };
    ushort16* xb      = (ushort16*)take((size_t)nNodes * CH * 2);      // 12.8 MB
    ushort16* mean_b  = (ushort16*)take((size_t)nNodes * CH * 2);      // 12.8 MB
    ushort16* wct     = (ushort16*)take((size_t)CH * 256 * 2);         // 64 KB
    // hist + bn_sum + bn_sumsq contiguous -> one memset covers all three
    int*      hist    = (int*)take((size_t)(nNodes + 256) * 4);
    float*    bn_sum  = (float*)(hist + nNodes);
    float*    bn_sumsq= bn_sum + CH;
    int*      rowptr  = (int*)take((size_t)(nNodes + 1) * 4);
    int*      cursor  = (int*)take((size_t)nNodes * 4);
    int*      colidx  = (int*)take((size_t)nEdges * 4);                // 3.2 MB
    float*    scaless = (float*)take(256 * 4);
    int*      flag    = (int*)take(4);

    float* h = (float*)d_out;

    hipMemsetAsync(hist, 0, (size_t)(nNodes + 256) * 4, stream);
    sage_detect<<<1, 64, 0, stream>>>((const int*)ei, flag);

    int eBlocks = (nEdges + 255) / 256;
    sage_hist<<<eBlocks, 256, 0, stream>>>(ei, flag, hist, nEdges);
    sage_scan<<<1, 1024, 0, stream>>>(hist, rowptr, cursor, nNodes);
    sage_fill<<<eBlocks, 256, 0, stream>>>(ei, flag, cursor, colidx, nEdges);

    int total8 = nNodes * CH / 8;
    sage_convert<<<(total8 + 255) / 256, 256, 0, stream>>>(x, (uint32*)xb, total8);
    sage_prep_wct<<<(CH * 256) / 256, 256, 0, stream>>>(Wl, Wr, wct);

    sage_aggregate<<<(nNodes + 3) / 4, 256, 0, stream>>>(
        xb, rowptr, colidx, (uint32*)mean_b, nNodes);

    sage_gemm<<<nBlkM, 256, 0, stream>>>(
        xb, mean_b, wct, bl, h, bn_sum, bn_sumsq, nNodes);

    sage_finalize<<<1, CH, 0, stream>>>(bn_sum, bn_sumsq, gamma, beta, scaless, nNodes);

    int total4 = nNodes * CH / 4;
    sage_apply<<<(total4 + 255) / 256, 256, 0, stream>>>(h, scaless, total4);
}

// Round 4
// 204.553 us; speedup vs baseline: 3.6929x; 1.3308x over previous
//
#include <hip/hip_runtime.h>

#define CH 128
#define BN_EPS 1e-5f

typedef unsigned int uint32;
typedef unsigned short ushort16;
using f32x4  = __attribute__((ext_vector_type(4))) float;
using bf16x8 = __attribute__((ext_vector_type(8))) short;

__device__ __forceinline__ ushort16 f2b(float f) {
    uint32 u = __float_as_uint(f);
    return (ushort16)((u + 0x7FFFu + ((u >> 16) & 1u)) >> 16);   // RNE
}
__device__ __forceinline__ float blo(uint32 u) { return __uint_as_float(u << 16); }
__device__ __forceinline__ float bhi(uint32 u) { return __uint_as_float(u & 0xFFFF0000u); }

// ---------------------------------------------------------------------------
// Linked-list CSR-free edge indexing:
//   head[d] -> last edge id with dst d (-1 terminator), pair[e] = {next, src}.
// One pass, coalesced 8B pair writes (vs 52 MB scattered-line traffic of the
// counting-sort fill). int64-vs-int32 edge_index detection done per-wave
// inline (ballot over the first 64 odd words; int64 -> all-zero high words).
__global__ __launch_bounds__(256) void sage_chain(
    const void* __restrict__ ei, int* __restrict__ head,
    int2* __restrict__ pair, int nEdges)
{
    const int* pi = (const int*)ei;
    int lane = threadIdx.x & 63;
    int probe = pi[lane * 2 + 1];
    bool is64 = (__ballot(probe != 0) == 0ULL);

    int e = blockIdx.x * 256 + threadIdx.x;
    if (e >= nEdges) return;
    int s, d;
    if (is64) {
        const long long* p = (const long long*)ei;
        s = (int)p[e];
        d = (int)p[nEdges + e];
    } else {
        s = pi[e];
        d = pi[nEdges + e];
    }
    int old = atomicExch(&head[d], e);
    pair[e] = make_int2(old, s);
}

// ---------------------------------------------------------------------------
// x (f32) -> xb (bf16), 8 elems/thread.
__global__ __launch_bounds__(256) void sage_convert(
    const float* __restrict__ x, uint32* __restrict__ xb4, int total8)
{
    int i = blockIdx.x * 256 + threadIdx.x;
    if (i >= total8) return;
    const float4* x4 = (const float4*)x;
    float4 a = x4[2 * i], b = x4[2 * i + 1];
    uint4 o;
    o.x = (uint32)f2b(a.x) | ((uint32)f2b(a.y) << 16);
    o.y = (uint32)f2b(a.z) | ((uint32)f2b(a.w) << 16);
    o.z = (uint32)f2b(b.x) | ((uint32)f2b(b.y) << 16);
    o.w = (uint32)f2b(b.z) | ((uint32)f2b(b.w) << 16);
    ((uint4*)xb4)[i] = o;
}

// ---------------------------------------------------------------------------
// WcT[co][k] bf16, k<128 -> W_r[co][k], k>=128 -> W_l[co][k-128].
__global__ __launch_bounds__(256) void sage_prep_wct(
    const float* __restrict__ Wl, const float* __restrict__ Wr,
    ushort16* __restrict__ wct)
{
    int idx = blockIdx.x * 256 + threadIdx.x;   // < 128*256
    int co = idx >> 8, k = idx & 255;
    float v = (k < 128) ? Wr[co * 128 + k] : Wl[co * 128 + (k - 128)];
    wct[idx] = f2b(v);
}

// ---------------------------------------------------------------------------
// Chain-walk gather: one wave per node. Per step: one wave-uniform 8B pair
// load (chain latency, hidden by TLP) + one coalesced 256B row gather from
// L3-resident xb. mean_b[n] = bf16(mean of xb[neighbors]).
__global__ __launch_bounds__(256) void sage_aggregate(
    const ushort16* __restrict__ xb, const int* __restrict__ head,
    const int2* __restrict__ pair, uint32* __restrict__ mean_b, int nNodes)
{
    int node = blockIdx.x * 4 + (threadIdx.x >> 6);
    if (node >= nNodes) return;
    int lane = threadIdx.x & 63;
    float ax = 0.f, ay = 0.f;
    int cnt = 0;
    int cur = head[node];
    while (cur >= 0) {
        int2 pr = pair[cur];
        uint32 u = *(const uint32*)((const char*)xb + ((size_t)pr.y << 8) + lane * 4);
        ax += blo(u);
        ay += bhi(u);
        ++cnt;
        cur = pr.x;
    }
    float inv = 1.0f / fmaxf((float)cnt, 1.0f);
    uint32 o = (uint32)f2b(ax * inv) | ((uint32)f2b(ay * inv) << 16);
    mean_b[(size_t)node * (CH / 2) + lane] = o;
}

// ---------------------------------------------------------------------------
// h[n][co] = sum_k Xc[n][k] * WcT[co][k] + bl[co], Xc = [xb | mean_b] (K=256).
// MFMA 16x16x32 bf16. Block = 256 thr = 4 waves x 16 rows = 64 rows, all 128 co.
// Fused BN partials -> one atomicAdd per channel per block.
__global__ __launch_bounds__(256) void sage_gemm(
    const ushort16* __restrict__ xb, const ushort16* __restrict__ mean_b,
    const ushort16* __restrict__ wct, const float* __restrict__ bl,
    float* __restrict__ h, float* __restrict__ bn_sum, float* __restrict__ bn_sumsq,
    int nNodes)
{
    __shared__ float redS[4][CH];
    __shared__ float redQ[4][CH];

    int tid = threadIdx.x;
    int wave = tid >> 6, lane = tid & 63;
    int col = lane & 15, kg = lane >> 4;
    int rowBase = blockIdx.x * 64 + wave * 16;

    int arow = min(rowBase + col, nNodes - 1);          // A-frag row = lane&15
    const ushort16* xrow = xb + (size_t)arow * CH;
    const ushort16* mrow = mean_b + (size_t)arow * CH;

    f32x4 acc[8];
    #pragma unroll
    for (int cb = 0; cb < 8; ++cb) acc[cb] = (f32x4){0.f, 0.f, 0.f, 0.f};

    #pragma unroll
    for (int kstep = 0; kstep < 8; ++kstep) {
        const ushort16* asrc = (kstep < 4) ? (xrow + kstep * 32 + kg * 8)
                                           : (mrow + (kstep - 4) * 32 + kg * 8);
        bf16x8 a = *(const bf16x8*)asrc;
        #pragma unroll
        for (int cb = 0; cb < 8; ++cb) {
            const ushort16* bsrc = wct + (size_t)(cb * 16 + col) * 256 + kstep * 32 + kg * 8;
            bf16x8 b = *(const bf16x8*)bsrc;
            acc[cb] = __builtin_amdgcn_mfma_f32_16x16x32_bf16(a, b, acc[cb], 0, 0, 0);
        }
    }

    // epilogue: bias, store h, BN partial sums
    #pragma unroll
    for (int cb = 0; cb < 8; ++cb) {
        int co = cb * 16 + col;
        float blv = bl[co];
        float s = 0.f, ss = 0.f;
        #pragma unroll
        for (int j = 0; j < 4; ++j) {
            int r = rowBase + kg * 4 + j;               // C row = (lane>>4)*4+j
            float v = acc[cb][j] + blv;
            if (r < nNodes) {
                h[(size_t)r * CH + co] = v;
                s += v;
                ss += v * v;
            }
        }
        s  += __shfl_xor(s, 16);  s  += __shfl_xor(s, 32);
        ss += __shfl_xor(ss, 16); ss += __shfl_xor(ss, 32);
        if (kg == 0) { redS[wave][co] = s; redQ[wave][co] = ss; }
    }
    __syncthreads();
    if (tid < CH) {
        atomicAdd(&bn_sum[tid], redS[0][tid] + redS[1][tid] + redS[2][tid] + redS[3][tid]);
    } else {
        int c = tid - CH;
        atomicAdd(&bn_sumsq[c], redQ[0][c] + redQ[1][c] + redQ[2][c] + redQ[3][c]);
    }
}

// ---------------------------------------------------------------------------
__global__ void sage_finalize(
    const float* __restrict__ bn_sum, const float* __restrict__ bn_sumsq,
    const float* __restrict__ gamma, const float* __restrict__ beta,
    float* __restrict__ scaleshift, int nNodes)
{
    int c = threadIdx.x;
    float invN = 1.0f / (float)nNodes;
    float mu = bn_sum[c] * invN;
    float var = bn_sumsq[c] * invN - mu * mu;
    var = fmaxf(var, 0.f);
    float sc = gamma[c] * rsqrtf(var + BN_EPS);
    scaleshift[c] = sc;
    scaleshift[CH + c] = beta[c] - mu * sc;
}

// ---------------------------------------------------------------------------
__global__ __launch_bounds__(256) void sage_apply(
    float* __restrict__ h, const float* __restrict__ scaleshift, int total4)
{
    int i = blockIdx.x * 256 + threadIdx.x;
    if (i >= total4) return;
    float4 v = reinterpret_cast<float4*>(h)[i];
    int c = (i * 4) & 127;
    float4 sc = *reinterpret_cast<const float4*>(&scaleshift[c]);
    float4 sh = *reinterpret_cast<const float4*>(&scaleshift[CH + c]);
    v.x = fmaxf(fmaf(v.x, sc.x, sh.x), 0.f);
    v.y = fmaxf(fmaf(v.y, sc.y, sh.y), 0.f);
    v.z = fmaxf(fmaf(v.z, sc.z, sh.z), 0.f);
    v.w = fmaxf(fmaf(v.w, sc.w, sh.w), 0.f);
    reinterpret_cast<float4*>(h)[i] = v;
}

// ---------------------------------------------------------------------------
extern "C" void kernel_launch(void* const* d_in, const int* in_sizes, int n_in,
                              void* d_out, int out_size, void* d_ws, size_t ws_size,
                              hipStream_t stream)
{
    const float* x     = (const float*)d_in[0];
    const void*  ei    = d_in[1];
    const float* Wl    = (const float*)d_in[2];
    const float* bl    = (const float*)d_in[3];
    const float* Wr    = (const float*)d_in[4];
    const float* gamma = (const float*)d_in[5];
    const float* beta  = (const float*)d_in[6];

    int nNodes = in_sizes[0] / CH;
    int nEdges = in_sizes[1] / 2;
    int nBlkM  = (nNodes + 63) / 64;

    // ws layout (256B-aligned slabs)
    char* p = (char*)d_ws;
    auto take = [&](size_t bytes) {
        char* r = p;
        p += (bytes + 255) & ~(size_t)255;
        return r;
    };
    ushort16* xb      = (ushort16*)take((size_t)nNodes * CH * 2);      // 12.8 MB
    ushort16* mean_b  = (ushort16*)take((size_t)nNodes * CH * 2);      // 12.8 MB
    ushort16* wct     = (ushort16*)take((size_t)CH * 256 * 2);         // 64 KB
    int*      head    = (int*)take((size_t)nNodes * 4);                // memset 0xFF
    float*    bn_sum  = (float*)take(256 * 4);                         // memset 0
    float*    bn_sumsq= bn_sum + CH;
    int2*     pair    = (int2*)take((size_t)nEdges * 8);               // 6.4 MB
    float*    scaless = (float*)take(256 * 4);

    float* h = (float*)d_out;

    hipMemsetAsync(head, 0xFF, (size_t)nNodes * 4, stream);            // head = -1
    hipMemsetAsync(bn_sum, 0, 256 * 4, stream);

    int eBlocks = (nEdges + 255) / 256;
    sage_chain<<<eBlocks, 256, 0, stream>>>(ei, head, pair, nEdges);

    int total8 = nNodes * CH / 8;
    sage_convert<<<(total8 + 255) / 256, 256, 0, stream>>>(x, (uint32*)xb, total8);
    sage_prep_wct<<<(CH * 256) / 256, 256, 0, stream>>>(Wl, Wr, wct);

    sage_aggregate<<<(nNodes + 3) / 4, 256, 0, stream>>>(
        xb, head, pair, (uint32*)mean_b, nNodes);

    sage_gemm<<<nBlkM, 256, 0, stream>>>(
        xb, mean_b, wct, bl, h, bn_sum, bn_sumsq, nNodes);

    sage_finalize<<<1, CH, 0, stream>>>(bn_sum, bn_sumsq, gamma, beta, scaless, nNodes);

    int total4 = nNodes * CH / 4;
    sage_apply<<<(total4 + 255) / 256, 256, 0, stream>>>(h, scaless, total4);
}

// Round 5
// 184.560 us; speedup vs baseline: 4.0930x; 1.1083x over previous
//
#include <hip/hip_runtime.h>

#define CH 128
#define BN_EPS 1e-5f

typedef unsigned int uint32;
typedef unsigned short ushort16;
using f32x4  = __attribute__((ext_vector_type(4))) float;
using bf16x8 = __attribute__((ext_vector_type(8))) short;

__device__ __forceinline__ ushort16 f2b(float f) {
    uint32 u = __float_as_uint(f);
    return (ushort16)((u + 0x7FFFu + ((u >> 16) & 1u)) >> 16);   // RNE
}
__device__ __forceinline__ float blo(uint32 u) { return __uint_as_float(u << 16); }
__device__ __forceinline__ float bhi(uint32 u) { return __uint_as_float(u & 0xFFFF0000u); }

// ---------------------------------------------------------------------------
// Fused prep kernel (grid = 3125 blocks x 256):
//  (a) edge-chain build: head[d] <- atomicExch, pair[e] = {next, src}
//      (int64-vs-int32 detect inline via ballot over first 64 odd words)
//  (b) x f32 -> xb bf16 (8 elems/thread, same e-range)
//  (c) blocks [0,128): WcT[co][k] bf16 build (k<128 -> Wr, k>=128 -> Wl)
//  (d) block 0: zero bn[0:256]
__global__ __launch_bounds__(256) void sage_prep(
    const float* __restrict__ x, const void* __restrict__ ei,
    const float* __restrict__ Wl, const float* __restrict__ Wr,
    int* __restrict__ head, int2* __restrict__ pair,
    uint32* __restrict__ xb4, ushort16* __restrict__ wct,
    float* __restrict__ bn, int nEdges, int total8)
{
    const int* pi = (const int*)ei;
    int lane = threadIdx.x & 63;
    int probe = pi[lane * 2 + 1];
    bool is64 = (__ballot(probe != 0) == 0ULL);

    int e = blockIdx.x * 256 + threadIdx.x;
    if (e < nEdges) {
        int s, d;
        if (is64) {
            const long long* p = (const long long*)ei;
            s = (int)p[e];
            d = (int)p[nEdges + e];
        } else {
            s = pi[e];
            d = pi[nEdges + e];
        }
        int old = atomicExch(&head[d], e);
        pair[e] = make_int2(old, s);
    }

    int i = blockIdx.x * 256 + threadIdx.x;
    if (i < total8) {
        const float4* x4 = (const float4*)x;
        float4 a = x4[2 * i], b = x4[2 * i + 1];
        uint4 o;
        o.x = (uint32)f2b(a.x) | ((uint32)f2b(a.y) << 16);
        o.y = (uint32)f2b(a.z) | ((uint32)f2b(a.w) << 16);
        o.z = (uint32)f2b(b.x) | ((uint32)f2b(b.y) << 16);
        o.w = (uint32)f2b(b.z) | ((uint32)f2b(b.w) << 16);
        ((uint4*)xb4)[i] = o;
    }

    if (blockIdx.x < 128) {
        int idx = blockIdx.x * 256 + threadIdx.x;    // covers 128*256 = CH*256
        int co = idx >> 8, k = idx & 255;
        float v = (k < 128) ? Wr[co * 128 + k] : Wl[co * 128 + (k - 128)];
        wct[idx] = f2b(v);
    }
    if (blockIdx.x == 0) bn[threadIdx.x] = 0.f;      // bn_sum[128] + bn_sumsq[128]
}

// ---------------------------------------------------------------------------
// Chain-walk gather, 4 interleaved chains per wave (4x MLP vs 1 chain/wave).
// Per step: 4 independent wave-uniform 8B pair loads, then 4 independent
// coalesced 256B row gathers. mean_b[n] = bf16(mean of xb[neighbors]).
__global__ __launch_bounds__(256) void sage_aggregate(
    const ushort16* __restrict__ xb, const int* __restrict__ head,
    const int2* __restrict__ pair, uint32* __restrict__ mean_b, int nNodes)
{
    int wid = blockIdx.x * 4 + (threadIdx.x >> 6);
    int nbase = wid * 4;
    if (nbase >= nNodes) return;
    int lane = threadIdx.x & 63;

    float ax[4] = {0.f, 0.f, 0.f, 0.f}, ay[4] = {0.f, 0.f, 0.f, 0.f};
    int cur[4], cnt[4] = {0, 0, 0, 0};
    #pragma unroll
    for (int c = 0; c < 4; ++c)
        cur[c] = (nbase + c < nNodes) ? head[nbase + c] : -1;

    while (cur[0] >= 0 || cur[1] >= 0 || cur[2] >= 0 || cur[3] >= 0) {
        int2 pr[4];
        #pragma unroll
        for (int c = 0; c < 4; ++c)
            if (cur[c] >= 0) pr[c] = pair[cur[c]];
        #pragma unroll
        for (int c = 0; c < 4; ++c) {
            if (cur[c] >= 0) {
                uint32 u = *(const uint32*)((const char*)xb + ((size_t)pr[c].y << 8) + lane * 4);
                ax[c] += blo(u);
                ay[c] += bhi(u);
                ++cnt[c];
                cur[c] = pr[c].x;
            }
        }
    }

    #pragma unroll
    for (int c = 0; c < 4; ++c) {
        int n = nbase + c;
        if (n < nNodes) {
            float inv = 1.0f / fmaxf((float)cnt[c], 1.0f);
            uint32 o = (uint32)f2b(ax[c] * inv) | ((uint32)f2b(ay[c] * inv) << 16);
            mean_b[(size_t)n * (CH / 2) + lane] = o;
        }
    }
}

// ---------------------------------------------------------------------------
// h[n][co] = sum_k Xc[n][k] * WcT[co][k] + bl[co], Xc = [xb | mean_b] (K=256).
// MFMA 16x16x32 bf16. Block = 256 thr = 4 waves x 16 rows = 64 rows, all 128 co.
// Fused BN partials -> one atomicAdd per channel per block.
__global__ __launch_bounds__(256) void sage_gemm(
    const ushort16* __restrict__ xb, const ushort16* __restrict__ mean_b,
    const ushort16* __restrict__ wct, const float* __restrict__ bl,
    float* __restrict__ h, float* __restrict__ bn, int nNodes)
{
    __shared__ float redS[4][CH];
    __shared__ float redQ[4][CH];

    int tid = threadIdx.x;
    int wave = tid >> 6, lane = tid & 63;
    int col = lane & 15, kg = lane >> 4;
    int rowBase = blockIdx.x * 64 + wave * 16;

    int arow = min(rowBase + col, nNodes - 1);          // A-frag row = lane&15
    const ushort16* xrow = xb + (size_t)arow * CH;
    const ushort16* mrow = mean_b + (size_t)arow * CH;

    f32x4 acc[8];
    #pragma unroll
    for (int cb = 0; cb < 8; ++cb) acc[cb] = (f32x4){0.f, 0.f, 0.f, 0.f};

    #pragma unroll
    for (int kstep = 0; kstep < 8; ++kstep) {
        const ushort16* asrc = (kstep < 4) ? (xrow + kstep * 32 + kg * 8)
                                           : (mrow + (kstep - 4) * 32 + kg * 8);
        bf16x8 a = *(const bf16x8*)asrc;
        #pragma unroll
        for (int cb = 0; cb < 8; ++cb) {
            const ushort16* bsrc = wct + (size_t)(cb * 16 + col) * 256 + kstep * 32 + kg * 8;
            bf16x8 b = *(const bf16x8*)bsrc;
            acc[cb] = __builtin_amdgcn_mfma_f32_16x16x32_bf16(a, b, acc[cb], 0, 0, 0);
        }
    }

    // epilogue: bias, store h, BN partial sums
    #pragma unroll
    for (int cb = 0; cb < 8; ++cb) {
        int co = cb * 16 + col;
        float blv = bl[co];
        float s = 0.f, ss = 0.f;
        #pragma unroll
        for (int j = 0; j < 4; ++j) {
            int r = rowBase + kg * 4 + j;               // C row = (lane>>4)*4+j
            float v = acc[cb][j] + blv;
            if (r < nNodes) {
                h[(size_t)r * CH + co] = v;
                s += v;
                ss += v * v;
            }
        }
        s  += __shfl_xor(s, 16);  s  += __shfl_xor(s, 32);
        ss += __shfl_xor(ss, 16); ss += __shfl_xor(ss, 32);
        if (kg == 0) { redS[wave][co] = s; redQ[wave][co] = ss; }
    }
    __syncthreads();
    if (tid < CH) {
        atomicAdd(&bn[tid], redS[0][tid] + redS[1][tid] + redS[2][tid] + redS[3][tid]);
    } else {
        int c = tid - CH;
        atomicAdd(&bn[CH + c], redQ[0][c] + redQ[1][c] + redQ[2][c] + redQ[3][c]);
    }
}

// ---------------------------------------------------------------------------
// Fused BN-finalize + apply: every block recomputes scale/shift from bn sums
// (128-wide, ~1us of redundant VALU), then normalizes+ReLUs its h slice.
__global__ __launch_bounds__(256) void sage_apply(
    float* __restrict__ h, const float* __restrict__ bn,
    const float* __restrict__ gamma, const float* __restrict__ beta,
    int total4, int nNodes)
{
    __shared__ float sc_sh[CH], sh_sh[CH];
    int tid = threadIdx.x;
    if (tid < CH) {
        float invN = 1.0f / (float)nNodes;
        float mu = bn[tid] * invN;
        float var = fmaxf(bn[CH + tid] * invN - mu * mu, 0.f);
        float sc = gamma[tid] * rsqrtf(var + BN_EPS);
        sc_sh[tid] = sc;
        sh_sh[tid] = beta[tid] - mu * sc;
    }
    __syncthreads();
    int i = blockIdx.x * 256 + tid;
    if (i >= total4) return;
    float4 v = reinterpret_cast<float4*>(h)[i];
    int c = (i * 4) & 127;
    float4 sc = *reinterpret_cast<const float4*>(&sc_sh[c]);
    float4 sh = *reinterpret_cast<const float4*>(&sh_sh[c]);
    v.x = fmaxf(fmaf(v.x, sc.x, sh.x), 0.f);
    v.y = fmaxf(fmaf(v.y, sc.y, sh.y), 0.f);
    v.z = fmaxf(fmaf(v.z, sc.z, sh.z), 0.f);
    v.w = fmaxf(fmaf(v.w, sc.w, sh.w), 0.f);
    reinterpret_cast<float4*>(h)[i] = v;
}

// ---------------------------------------------------------------------------
extern "C" void kernel_launch(void* const* d_in, const int* in_sizes, int n_in,
                              void* d_out, int out_size, void* d_ws, size_t ws_size,
                              hipStream_t stream)
{
    const float* x     = (const float*)d_in[0];
    const void*  ei    = d_in[1];
    const float* Wl    = (const float*)d_in[2];
    const float* bl    = (const float*)d_in[3];
    const float* Wr    = (const float*)d_in[4];
    const float* gamma = (const float*)d_in[5];
    const float* beta  = (const float*)d_in[6];

    int nNodes = in_sizes[0] / CH;
    int nEdges = in_sizes[1] / 2;
    int nBlkM  = (nNodes + 63) / 64;

    // ws layout (256B-aligned slabs)
    char* p = (char*)d_ws;
    auto take = [&](size_t bytes) {
        char* r = p;
        p += (bytes + 255) & ~(size_t)255;
        return r;
    };
    ushort16* xb      = (ushort16*)take((size_t)nNodes * CH * 2);      // 12.8 MB
    ushort16* mean_b  = (ushort16*)take((size_t)nNodes * CH * 2);      // 12.8 MB
    ushort16* wct     = (ushort16*)take((size_t)CH * 256 * 2);         // 64 KB
    int*      head    = (int*)take((size_t)nNodes * 4);                // memset 0xFF
    float*    bn      = (float*)take(256 * 4);                         // zeroed in prep
    int2*     pair    = (int2*)take((size_t)nEdges * 8);               // 6.4 MB

    float* h = (float*)d_out;

    hipMemsetAsync(head, 0xFF, (size_t)nNodes * 4, stream);            // head = -1

    int total8 = nNodes * CH / 8;
    int eBlocks = (nEdges + 255) / 256;
    int pBlocks = max(eBlocks, (total8 + 255) / 256);
    sage_prep<<<pBlocks, 256, 0, stream>>>(
        x, ei, Wl, Wr, head, pair, (uint32*)xb, wct, bn, nEdges, total8);

    int aBlocks = ((nNodes + 3) / 4 + 3) / 4;   // 4 nodes/wave, 4 waves/block
    sage_aggregate<<<aBlocks, 256, 0, stream>>>(
        xb, head, pair, (uint32*)mean_b, nNodes);

    sage_gemm<<<nBlkM, 256, 0, stream>>>(
        xb, mean_b, wct, bl, h, bn, nNodes);

    int total4 = nNodes * CH / 4;
    sage_apply<<<(total4 + 255) / 256, 256, 0, stream>>>(
        h, bn, gamma, beta, total4, nNodes);
}